// Round 5
// baseline (485.813 us; speedup 1.0000x reference)
//
#include <hip/hip_runtime.h>

#define BB 64
#define NN 128
#define INF_ 5
#define LATD 3
#define HIDD 64

// ---------------------------------------------------------------------------
// ALL inputs are float32 (reference: jnp.float32; values bf16-rounded but
// f32-stored). Rounds 1-4 failed from casting d_in to bf16 — reading the
// wrong halfwords manufactured NaNs in a "verbatim copy" output.
// d_out is float32 (reference outputs f32/bool).
// ---------------------------------------------------------------------------

// ---------------------------------------------------------------------------
// Encoder: batch[B,N,5] -> h1 -> h2 -> latent. f64 so Gabriel boundary
// decisions (d2 < r2) track a float64 np reference bit-for-bit in practice.
// Also emits o0 = batch[:,:,:4], o1 = batch[:,:,4:5], o4 = latent (f32).
// Grid (B,4): 32 nodes per block; wave-per-node, lane = hidden index.
// ---------------------------------------------------------------------------
__global__ __launch_bounds__(256) void enc_kernel(
    const float* __restrict__ batch,
    const float* __restrict__ w1, const float* __restrict__ b1,
    const float* __restrict__ w2, const float* __restrict__ b2,
    const float* __restrict__ w3, const float* __restrict__ b3,
    double* __restrict__ lat64,
    float* __restrict__ o0, float* __restrict__ o1, float* __restrict__ o4)
{
    const int b = blockIdx.x;
    const int n0 = blockIdx.y * 32;
    const int tid = threadIdx.x;
    const int w = tid >> 6, lane = tid & 63;

    __shared__ double xs[32][6];
    __shared__ double w1s[INF_][HIDD];
    __shared__ float  w2s[HIDD * HIDD];
    __shared__ double w3s[HIDD][LATD];
    __shared__ double b1s[HIDD], b2s[HIDD], b3s[LATD];

    for (int idx = tid; idx < 32 * INF_; idx += 256) {
        int n = idx / INF_, c = idx % INF_;
        float v = batch[((size_t)b * NN + n0 + n) * INF_ + c];
        xs[n][c] = (double)v;
        if (c < 4) o0[((size_t)b * NN + n0 + n) * 4 + c] = v;
        else       o1[(size_t)b * NN + n0 + n] = v;
    }
    for (int idx = tid; idx < INF_ * HIDD; idx += 256)
        w1s[idx / HIDD][idx % HIDD] = (double)w1[idx];
    for (int idx = tid; idx < HIDD * HIDD; idx += 256)
        w2s[idx] = w2[idx];
    for (int idx = tid; idx < HIDD * LATD; idx += 256)
        w3s[idx / LATD][idx % LATD] = (double)w3[idx];
    if (tid < HIDD) {
        b1s[tid] = (double)b1[tid];
        b2s[tid] = (double)b2[tid];
    }
    if (tid < LATD) b3s[tid] = (double)b3[tid];
    __syncthreads();

    for (int r = 0; r < 8; ++r) {
        const int nl = w * 8 + r;
        const int n = n0 + nl;
        double h1v = b1s[lane];
        for (int k = 0; k < INF_; ++k) h1v += xs[nl][k] * w1s[k][lane];
        h1v = fmax(h1v, 0.0);
        double h2v = b2s[lane];
        for (int k = 0; k < HIDD; ++k) {
            double h1k = __shfl(h1v, k, 64);
            h2v += h1k * (double)w2s[k * HIDD + lane];
        }
        h2v = fmax(h2v, 0.0);
        double l0 = h2v * w3s[lane][0];
        double l1 = h2v * w3s[lane][1];
        double l2 = h2v * w3s[lane][2];
        for (int o = 32; o >= 1; o >>= 1) {
            l0 += __shfl_xor(l0, o, 64);
            l1 += __shfl_xor(l1, o, 64);
            l2 += __shfl_xor(l2, o, 64);
        }
        l0 += b3s[0]; l1 += b3s[1]; l2 += b3s[2];
        if (lane < LATD) {
            double lv = (lane == 0) ? l0 : ((lane == 1) ? l1 : l2);
            lat64[((size_t)b * NN + n) * LATD + lane] = lv;
            o4[((size_t)b * NN + n) * LATD + lane] = (float)lv;  // o4 doubles as latf
        }
    }
}

// ---------------------------------------------------------------------------
// Gabriel graph: block per (i,b), thread = j. f64, mirrors reference exprs:
// d2 = pk2[k] - 2*dot(p_k, mid) + m2 ; blocked = any(d2 < r2 & k!=i & k!=j).
// Writes o5 (adj f32 0/1) and o6 (edge_dist f32). GAT reads adjacency from
// o5 (self-loops added in-kernel) -> no adjacency scratch.
// ---------------------------------------------------------------------------
__global__ __launch_bounds__(128) void gabriel_kernel(
    const double* __restrict__ lat64,
    float* __restrict__ o5, float* __restrict__ o6)
{
    const int i = blockIdx.x, b = blockIdx.y, j = threadIdx.x;
    __shared__ double px[NN], py[NN], pz[NN], pk2[NN];
    const double* L = lat64 + (size_t)b * NN * LATD;
    double x = L[j * LATD + 0], y = L[j * LATD + 1], z = L[j * LATD + 2];
    px[j] = x; py[j] = y; pz[j] = z;
    pk2[j] = x * x + y * y + z * z;
    __syncthreads();
    double pix = px[i], piy = py[i], piz = pz[i];
    double dx = pix - x, dy = piy - y, dz = piz - z;
    double s2 = dx * dx + dy * dy + dz * dz;
    double r2 = 0.25 * s2;
    double mx = 0.5 * (pix + x), my = 0.5 * (piy + y), mz = 0.5 * (piz + z);
    double m2 = mx * mx + my * my + mz * mz;
    bool blocked = false;
    for (int k = 0; k < NN; ++k) {
        double dot = px[k] * mx + py[k] * my + pz[k] * mz;
        double d2 = pk2[k] - 2.0 * dot + m2;
        blocked = blocked || ((d2 < r2) && (k != i) && (k != j));
        if ((k & 31) == 31 && __all(blocked)) break;
    }
    bool a = (!blocked) && (i != j);
    size_t off = ((size_t)b * NN + i) * NN + j;
    o5[off] = a ? 1.0f : 0.0f;
    o6[off] = a ? (float)sqrt(s2) : 0.0f;
}

// ---------------------------------------------------------------------------
// Fused linear + GATv2 layer. Block = 16 rows of one batch (grid BB*8).
// Prologue: compute hl for ALL 128 nodes into LDS f32 [128][65] (stride 65
// -> 2-way bank aliasing in both phases = free) and hr for this block's 16
// rows. x is read from global inside the loops (wave-uniform address ->
// broadcast, L1-served) to keep LDS ~42 KB. Main loop per wave, 4 rows:
// Phase A scores (lane=j, two halves) -> shuffle softmax -> Phase B
// aggregation (lane=h). Skip recomputed from latf (3x64 dot). C>0 fuses the
// output head (f32 write to d_out).
// ---------------------------------------------------------------------------
template <int CIN, int C>
__global__ __launch_bounds__(256) void gat_kernel(
    const float* __restrict__ xin,     // [B,N,CIN] f32 (CIN==64), else null
    const float* __restrict__ latf,    // [B,N,3] f32 (o4 region: x0 + skip src)
    const float* __restrict__ wl, const float* __restrict__ bl,
    const float* __restrict__ wr, const float* __restrict__ br,
    const float* __restrict__ att, const float* __restrict__ bias,
    const float* __restrict__ adjf,    // o5 region, f32 0/1 (no self loops)
    const float* __restrict__ skw, const float* __restrict__ skb, // null = no skip
    float* __restrict__ xout,          // C==0
    const float* __restrict__ head_w, const float* __restrict__ head_b,
    float* __restrict__ head_out)      // C>0
{
    const int bx = blockIdx.x;
    const int b = bx >> 3, i0 = (bx & 7) << 4;
    const int tid = threadIdx.x, w = tid >> 6, lane = tid & 63;

    __shared__ float hls[NN * 65];                        // 33.3 KB
    __shared__ float xs1[(CIN == 1) ? NN : 1];
    __shared__ float hrs[16 * HIDD];                      // 4 KB
    __shared__ float as_[4][NN];                          // 2 KB
    __shared__ float atts[HIDD], bsv[HIDD], blv[HIDD], brv[HIDD];
    __shared__ float hws[(C > 0) ? HIDD * C : 1];
    __shared__ float hbs[(C > 0) ? C : 1];
    __shared__ float sws[LATD * HIDD], sbs[HIDD];
    __shared__ float latr[16 * LATD];

    // ---- prologue: small params ----
    if constexpr (CIN == 1) {
        for (int j = tid; j < NN; j += 256)
            xs1[j] = latf[((size_t)b * NN + j) * LATD + 2];  // x0 = latent[...,2]
    }
    if (tid < HIDD) {
        atts[tid] = att[tid];  bsv[tid] = bias[tid];
        blv[tid]  = bl[tid];   brv[tid] = br[tid];
    }
    if constexpr (C > 0) {
        for (int idx = tid; idx < HIDD * C; idx += 256) hws[idx] = head_w[idx];
        if (tid < C) hbs[tid] = head_b[tid];
    }
    if (skw != nullptr) {
        for (int idx = tid; idx < LATD * HIDD; idx += 256) sws[idx] = skw[idx];
        if (tid < HIDD) sbs[tid] = skb[tid];
        for (int idx = tid; idx < 16 * LATD; idx += 256)
            latr[idx] = latf[((size_t)b * NN + i0) * LATD + idx];
    }
    __syncthreads();

    // ---- hl for all 128 nodes; hr for our 16 rows ----
    {
        const int h = tid & 63;
        const float* xb = (CIN == 64) ? (xin + (size_t)b * NN * HIDD) : nullptr;
        float wcol[CIN];
        #pragma unroll
        for (int k = 0; k < CIN; ++k) wcol[k] = wl[k * HIDD + h];
        const float bb = blv[h];
        const int jbase = (tid >> 6) * 32;
        for (int m = 0; m < 32; ++m) {
            const int j = jbase + m;
            float acc = bb;
            if constexpr (CIN == 64) {
                const float* xr = xb + j * HIDD;
                #pragma unroll
                for (int k = 0; k < CIN; ++k) acc = fmaf(xr[k], wcol[k], acc);
            } else {
                acc = fmaf(xs1[j], wcol[0], acc);
            }
            hls[j * 65 + h] = acc;
        }
        #pragma unroll
        for (int k = 0; k < CIN; ++k) wcol[k] = wr[k * HIDD + h];
        const float bb2 = brv[h];
        for (int m = 0; m < 4; ++m) {
            const int il = (tid >> 6) * 4 + m;
            const int j = i0 + il;
            float acc = bb2;
            if constexpr (CIN == 64) {
                const float* xr = xb + j * HIDD;
                #pragma unroll
                for (int k = 0; k < CIN; ++k) acc = fmaf(xr[k], wcol[k], acc);
            } else {
                acc = fmaf(xs1[j], wcol[0], acc);
            }
            hrs[il * HIDD + h] = acc;
        }
    }
    __syncthreads();

    // ---- per-wave: 4 rows each ----
    for (int r = 0; r < 4; ++r) {
        const int il = w * 4 + r, i = i0 + il;
        // Phase A: scores, lane = j (two halves)
        float s0, s1;
        {
            const float* hrr = hrs + il * HIDD;
            const float* hl0 = hls + lane * 65;
            const float* hl1 = hls + (lane + 64) * 65;
            float acc0 = 0.f, acc1 = 0.f;
            for (int h = 0; h < HIDD; ++h) {
                float rv = hrr[h], av = atts[h];
                float e0 = rv + hl0[h]; e0 = (e0 > 0.f) ? e0 : 0.2f * e0;
                float e1 = rv + hl1[h]; e1 = (e1 > 0.f) ? e1 : 0.2f * e1;
                acc0 = fmaf(av, e0, acc0);
                acc1 = fmaf(av, e1, acc1);
            }
            const float* arow = adjf + ((size_t)b * NN + i) * NN;
            bool a0 = (arow[lane] != 0.f)      || (lane == i);
            bool a1 = (arow[lane + 64] != 0.f) || (lane + 64 == i);
            s0 = a0 ? acc0 : -1e30f;
            s1 = a1 ? acc1 : -1e30f;
        }
        // softmax over 128 j
        float mxv = fmaxf(s0, s1);
        for (int o = 32; o >= 1; o >>= 1) mxv = fmaxf(mxv, __shfl_xor(mxv, o, 64));
        float e0 = __expf(s0 - mxv), e1 = __expf(s1 - mxv);
        float sm = e0 + e1;
        for (int o = 32; o >= 1; o >>= 1) sm += __shfl_xor(sm, o, 64);
        float inv = 1.f / sm;
        as_[w][lane]      = e0 * inv;
        as_[w][lane + 64] = e1 * inv;
        __syncthreads();
        // Phase B: aggregation, lane = h
        float acc = 0.f;
        const float* aw = as_[w];
        for (int j = 0; j < NN; ++j) acc = fmaf(aw[j], hls[j * 65 + lane], acc);
        float out = acc + bsv[lane];
        if (skw != nullptr) {
            const float* lr = latr + il * LATD;
            float sk = sbs[lane];
            sk = fmaf(lr[0], sws[0 * HIDD + lane], sk);
            sk = fmaf(lr[1], sws[1 * HIDD + lane], sk);
            sk = fmaf(lr[2], sws[2 * HIDD + lane], sk);
            out += 0.1f * sk;
        }
        out = fmaxf(out, 0.f);
        if constexpr (C == 0) {
            xout[((size_t)b * NN + i) * HIDD + lane] = out;
        } else {
            float hv[C > 0 ? C : 1];
            #pragma unroll
            for (int c = 0; c < C; ++c) {
                float v = out * hws[lane * C + c];
                for (int o = 32; o >= 1; o >>= 1) v += __shfl_xor(v, o, 64);
                hv[c] = v + hbs[c];
            }
            if (lane == 0)
                for (int c = 0; c < C; ++c)
                    head_out[((size_t)b * NN + i) * C + c] = hv[c];
        }
        __syncthreads();
    }
}

// ---------------------------------------------------------------------------
extern "C" void kernel_launch(void* const* d_in, const int* in_sizes, int n_in,
                              void* d_out, int out_size, void* d_ws, size_t ws_size,
                              hipStream_t stream)
{
    // ALL inputs float32 (see header comment).
    const float* batch  = (const float*)d_in[0];
    const float* enc_w1 = (const float*)d_in[1];
    const float* enc_b1 = (const float*)d_in[2];
    const float* enc_w2 = (const float*)d_in[3];
    const float* enc_b2 = (const float*)d_in[4];
    const float* enc_w3 = (const float*)d_in[5];
    const float* enc_b3 = (const float*)d_in[6];
    const float* g_wl[4]  = {(const float*)d_in[7],  (const float*)d_in[13], (const float*)d_in[19], (const float*)d_in[25]};
    const float* g_bl[4]  = {(const float*)d_in[8],  (const float*)d_in[14], (const float*)d_in[20], (const float*)d_in[26]};
    const float* g_wr[4]  = {(const float*)d_in[9],  (const float*)d_in[15], (const float*)d_in[21], (const float*)d_in[27]};
    const float* g_br[4]  = {(const float*)d_in[10], (const float*)d_in[16], (const float*)d_in[22], (const float*)d_in[28]};
    const float* g_att[4] = {(const float*)d_in[11], (const float*)d_in[17], (const float*)d_in[23], (const float*)d_in[29]};
    const float* g_b[4]   = {(const float*)d_in[12], (const float*)d_in[18], (const float*)d_in[24], (const float*)d_in[30]};
    const float* lab_w = (const float*)d_in[31];
    const float* lab_b = (const float*)d_in[32];
    const float* val_w = (const float*)d_in[33];
    const float* val_b = (const float*)d_in[34];
    const float* skw   = (const float*)d_in[35];
    const float* skb   = (const float*)d_in[36];

    float* out = (float*)d_out;
    float* o0 = out;            // batch[:,:,:4]   32768
    float* o1 = out + 32768;    // batch[:,:,4:5]   8192
    float* o2 = out + 40960;    // logits          32768
    float* o3 = out + 73728;    // values           8192
    float* o4 = out + 81920;    // latent          24576  (also serves as latf)
    float* o5 = out + 106496;   // adj           1048576
    float* o6 = out + 1155072;  // edge_dist     1048576

    // Scratch: 4.2 MB in d_ws. (Rounds 1-2 carved 11.8 MB with successful
    // launches, so this is safely within ws_size.)
    char* p = (char*)d_ws;
    auto carve = [&](size_t bytes) { void* r = (void*)p; p += (bytes + 255) & ~(size_t)255; return r; };
    double* lat64 = (double*)carve((size_t)BB * NN * LATD * 8);   // 196,608
    float*  xA    = (float*) carve((size_t)BB * NN * HIDD * 4);   // 2 MB
    float*  xB    = (float*) carve((size_t)BB * NN * HIDD * 4);   // 2 MB

    enc_kernel<<<dim3(BB, 4), 256, 0, stream>>>(batch, enc_w1, enc_b1, enc_w2, enc_b2,
                                                enc_w3, enc_b3, lat64, o0, o1, o4);
    gabriel_kernel<<<dim3(NN, BB), 128, 0, stream>>>(lat64, o5, o6);

    // layer 1 (Cin=1, x0 from o4/latf) -> xA
    gat_kernel<1, 0><<<BB * 8, 256, 0, stream>>>(nullptr, o4,
        g_wl[0], g_bl[0], g_wr[0], g_br[0], g_att[0], g_b[0], o5,
        nullptr, nullptr, xA, nullptr, nullptr, nullptr);
    // layer 2 -> xB (= x2, feeds layers 3 and 4)
    gat_kernel<64, 0><<<BB * 8, 256, 0, stream>>>(xA, o4,
        g_wl[1], g_bl[1], g_wr[1], g_br[1], g_att[1], g_b[1], o5,
        nullptr, nullptr, xB, nullptr, nullptr, nullptr);
    // layer 3 + skip + label head -> o2
    gat_kernel<64, 4><<<BB * 8, 256, 0, stream>>>(xB, o4,
        g_wl[2], g_bl[2], g_wr[2], g_br[2], g_att[2], g_b[2], o5,
        skw, skb, nullptr, lab_w, lab_b, o2);
    // layer 4 + skip + value head -> o3
    gat_kernel<64, 1><<<BB * 8, 256, 0, stream>>>(xB, o4,
        g_wl[3], g_bl[3], g_wr[3], g_br[3], g_att[3], g_b[3], o5,
        skw, skb, nullptr, val_w, val_b, o3);
}

// Round 6
// 411.534 us; speedup vs baseline: 1.1805x; 1.1805x over previous
//
#include <hip/hip_runtime.h>

#define BB 64
#define NN 128
#define INF_ 5
#define LATD 3
#define HIDD 64

struct P4d { double x, y, z, w; };   // {latent xyz, pk2} AoS for gabriel

__device__ __forceinline__ float bflo(unsigned u) { return __uint_as_float(u << 16); }
__device__ __forceinline__ float bfhi(unsigned u) { return __uint_as_float(u & 0xffff0000u); }
__device__ __forceinline__ unsigned bfpack(float a, float b) {
    unsigned ua = __float_as_uint(a), ub = __float_as_uint(b);
    unsigned ra = (ua + 0x7fffu + ((ua >> 16) & 1u)) >> 16;   // RNE
    unsigned rb = (ub + 0x7fffu + ((ub >> 16) & 1u)) >> 16;
    return ra | (rb << 16);
}

// ---------------------------------------------------------------------------
// Encoder (f64, unchanged math -> adjacency bits preserved). Emits AoS
// {x,y,z,pk2} f64 for gabriel, o0/o1/o4 (f32). Grid (B,4), 32 nodes/block.
// ---------------------------------------------------------------------------
__global__ __launch_bounds__(256) void enc_kernel(
    const float* __restrict__ batch,
    const float* __restrict__ w1, const float* __restrict__ b1,
    const float* __restrict__ w2, const float* __restrict__ b2,
    const float* __restrict__ w3, const float* __restrict__ b3,
    double* __restrict__ aos,
    float* __restrict__ o0, float* __restrict__ o1, float* __restrict__ o4)
{
    const int b = blockIdx.x;
    const int n0 = blockIdx.y * 32;
    const int tid = threadIdx.x;
    const int w = tid >> 6, lane = tid & 63;

    __shared__ double xs[32][6];
    __shared__ double w1s[INF_][HIDD];
    __shared__ float  w2s[HIDD * HIDD];
    __shared__ double w3s[HIDD][LATD];
    __shared__ double b1s[HIDD], b2s[HIDD], b3s[LATD];

    for (int idx = tid; idx < 32 * INF_; idx += 256) {
        int n = idx / INF_, c = idx % INF_;
        float v = batch[((size_t)b * NN + n0 + n) * INF_ + c];
        xs[n][c] = (double)v;
        if (c < 4) o0[((size_t)b * NN + n0 + n) * 4 + c] = v;
        else       o1[(size_t)b * NN + n0 + n] = v;
    }
    for (int idx = tid; idx < INF_ * HIDD; idx += 256)
        w1s[idx / HIDD][idx % HIDD] = (double)w1[idx];
    for (int idx = tid; idx < HIDD * HIDD; idx += 256)
        w2s[idx] = w2[idx];
    for (int idx = tid; idx < HIDD * LATD; idx += 256)
        w3s[idx / LATD][idx % LATD] = (double)w3[idx];
    if (tid < HIDD) {
        b1s[tid] = (double)b1[tid];
        b2s[tid] = (double)b2[tid];
    }
    if (tid < LATD) b3s[tid] = (double)b3[tid];
    __syncthreads();

    for (int r = 0; r < 8; ++r) {
        const int nl = w * 8 + r;
        const int n = n0 + nl;
        double h1v = b1s[lane];
        for (int k = 0; k < INF_; ++k) h1v += xs[nl][k] * w1s[k][lane];
        h1v = fmax(h1v, 0.0);
        double h2v = b2s[lane];
        for (int k = 0; k < HIDD; ++k) {
            double h1k = __shfl(h1v, k, 64);
            h2v += h1k * (double)w2s[k * HIDD + lane];
        }
        h2v = fmax(h2v, 0.0);
        double l0 = h2v * w3s[lane][0];
        double l1 = h2v * w3s[lane][1];
        double l2 = h2v * w3s[lane][2];
        for (int o = 32; o >= 1; o >>= 1) {
            l0 += __shfl_xor(l0, o, 64);
            l1 += __shfl_xor(l1, o, 64);
            l2 += __shfl_xor(l2, o, 64);
        }
        l0 += b3s[0]; l1 += b3s[1]; l2 += b3s[2];
        if (lane == 0) {
            double* A = aos + ((size_t)b * NN + n) * 4;
            A[0] = l0; A[1] = l1; A[2] = l2;
            A[3] = l0 * l0 + l1 * l1 + l2 * l2;        // pk2, same expr as before
        }
        if (lane < LATD) {
            double lv = (lane == 0) ? l0 : ((lane == 1) ? l1 : l2);
            o4[((size_t)b * NN + n) * LATD + lane] = (float)lv;  // o4 = latf
        }
    }
}

// ---------------------------------------------------------------------------
// Gabriel graph, LDS-free. Round-5 was LDS-issue-bound (4 broadcast
// ds_read_b64 per witness k -> 82 us modeled vs 94 measured). Witness points
// now come from AoS global via wave-uniform loads (scalar-cache path);
// per-lane point is a coalesced 32B load. f64 expressions byte-identical.
// ---------------------------------------------------------------------------
__global__ __launch_bounds__(128) void gabriel_kernel(
    const P4d* __restrict__ aos,
    float* __restrict__ o5, float* __restrict__ o6)
{
    const int i = blockIdx.x, b = blockIdx.y, j = threadIdx.x;
    const P4d* __restrict__ P = aos + (size_t)b * NN;
    P4d pj = P[j];
    P4d pi = P[i];                                  // uniform
    double dx = pi.x - pj.x, dy = pi.y - pj.y, dz = pi.z - pj.z;
    double s2 = dx * dx + dy * dy + dz * dz;
    double r2 = 0.25 * s2;
    double mx = 0.5 * (pi.x + pj.x), my = 0.5 * (pi.y + pj.y), mz = 0.5 * (pi.z + pj.z);
    double m2 = mx * mx + my * my + mz * mz;
    bool blocked = (j == i);   // vote-only: lane i never blocks, would kill __all exit
    for (int k = 0; k < NN; ++k) {
        P4d pk = P[k];                              // uniform -> s_load
        double dot = pk.x * mx + pk.y * my + pk.z * mz;
        double d2 = pk.w - 2.0 * dot + m2;
        blocked = blocked || ((d2 < r2) && (k != i) && (k != j));
        if ((k & 15) == 15 && __all(blocked)) break;
    }
    bool a = (!blocked) && (i != j);
    size_t off = ((size_t)b * NN + i) * NN + j;
    o5[off] = a ? 1.0f : 0.0f;
    o6[off] = a ? (float)sqrt(s2) : 0.0f;
}

// ---------------------------------------------------------------------------
// Fused linear + GATv2. Grid BB*4 (32 rows/block, 1 block/CU at 256 blocks).
// Stage x as packed-bf16 LDS (16 KB, error ~4e-3 vs 300x threshold margin);
// weights in per-lane registers (coalesced global reads). hl for all 128
// nodes -> LDS f32 [128][65] (2-way bank aliasing = free). Each lane hoists
// its two hl rows into 128 unrolled registers -> Phase A is register-math +
// hr broadcasts only. No per-row barriers (as_ is per-wave). C>0 fuses the
// output head.
// ---------------------------------------------------------------------------
template <int CIN, int C>
__global__ __launch_bounds__(256) void gat_kernel(
    const float* __restrict__ xin,     // [B,N,64] f32 (CIN==64), else null
    const float* __restrict__ latf,    // o4 region: x0 + skip source
    const float* __restrict__ wl, const float* __restrict__ bl,
    const float* __restrict__ wr, const float* __restrict__ br,
    const float* __restrict__ att, const float* __restrict__ bias,
    const float* __restrict__ adjf,    // o5 region, f32 0/1 (no self loops)
    const float* __restrict__ skw, const float* __restrict__ skb,
    float* __restrict__ xout,          // C==0
    const float* __restrict__ head_w, const float* __restrict__ head_b,
    float* __restrict__ head_out)      // C>0
{
    const int bx = blockIdx.x;
    const int b = bx >> 2, i0 = (bx & 3) << 5;     // 32 rows per block
    const int tid = threadIdx.x, w = tid >> 6, lane = tid & 63;

    __shared__ float    hls[NN * 65];                        // 33.3 KB
    __shared__ unsigned xsb[(CIN == 64) ? NN * 32 : 1];      // 16 KB bf16-packed
    __shared__ float    xs1[(CIN == 1) ? NN : 1];
    __shared__ float    hrs[32 * HIDD];                      // 8 KB
    __shared__ float    as_[4][NN];                          // 2 KB
    __shared__ float    atts[HIDD], bsv[HIDD];
    __shared__ float    hws[(C > 0) ? HIDD * C : 1];
    __shared__ float    hbs[(C > 0) ? C : 1];
    __shared__ float    sws[LATD * HIDD], sbs[HIDD];
    __shared__ float    latr[32 * LATD];

    // ---- stage x + params ----
    if constexpr (CIN == 64) {
        const float2* x2 = (const float2*)(xin + (size_t)b * NN * HIDD);
        for (int idx = tid; idx < NN * 32; idx += 256) {
            float2 v = x2[idx];
            xsb[idx] = bfpack(v.x, v.y);
        }
    } else {
        for (int j = tid; j < NN; j += 256)
            xs1[j] = latf[((size_t)b * NN + j) * LATD + 2];
    }
    if (tid < HIDD) { atts[tid] = att[tid]; bsv[tid] = bias[tid]; }
    if constexpr (C > 0) {
        for (int idx = tid; idx < HIDD * C; idx += 256) hws[idx] = head_w[idx];
        if (tid < C) hbs[tid] = head_b[tid];
    }
    if (skw != nullptr) {
        for (int idx = tid; idx < LATD * HIDD; idx += 256) sws[idx] = skw[idx];
        if (tid < HIDD) sbs[tid] = skb[tid];
        for (int idx = tid; idx < 32 * LATD; idx += 256)
            latr[idx] = latf[((size_t)b * NN + i0) * LATD + idx];
    }
    __syncthreads();

    // ---- hl (all 128 nodes, wave covers 32 j) + hr (wave's 8 rows) ----
    {
        const int h = lane;
        float wcol[CIN];
        #pragma unroll
        for (int k = 0; k < CIN; ++k) wcol[k] = wl[k * HIDD + h];
        const float bb = bl[h];
        const uint4* xq = (const uint4*)xsb;
        for (int m = 0; m < 32; ++m) {
            const int j = w * 32 + m;
            float acc = bb;
            if constexpr (CIN == 64) {
                #pragma unroll
                for (int t = 0; t < 8; ++t) {
                    uint4 q = xq[j * 8 + t];
                    acc = fmaf(bflo(q.x), wcol[8 * t + 0], acc);
                    acc = fmaf(bfhi(q.x), wcol[8 * t + 1], acc);
                    acc = fmaf(bflo(q.y), wcol[8 * t + 2], acc);
                    acc = fmaf(bfhi(q.y), wcol[8 * t + 3], acc);
                    acc = fmaf(bflo(q.z), wcol[8 * t + 4], acc);
                    acc = fmaf(bfhi(q.z), wcol[8 * t + 5], acc);
                    acc = fmaf(bflo(q.w), wcol[8 * t + 6], acc);
                    acc = fmaf(bfhi(q.w), wcol[8 * t + 7], acc);
                }
            } else {
                acc = fmaf(xs1[j], wcol[0], acc);
            }
            hls[j * 65 + h] = acc;
        }
        #pragma unroll
        for (int k = 0; k < CIN; ++k) wcol[k] = wr[k * HIDD + h];
        const float bb2 = br[h];
        for (int m = 0; m < 8; ++m) {
            const int il = w * 8 + m;
            const int j = i0 + il;
            float acc = bb2;
            if constexpr (CIN == 64) {
                #pragma unroll
                for (int t = 0; t < 8; ++t) {
                    uint4 q = xq[j * 8 + t];
                    acc = fmaf(bflo(q.x), wcol[8 * t + 0], acc);
                    acc = fmaf(bfhi(q.x), wcol[8 * t + 1], acc);
                    acc = fmaf(bflo(q.y), wcol[8 * t + 2], acc);
                    acc = fmaf(bfhi(q.y), wcol[8 * t + 3], acc);
                    acc = fmaf(bflo(q.z), wcol[8 * t + 4], acc);
                    acc = fmaf(bfhi(q.z), wcol[8 * t + 5], acc);
                    acc = fmaf(bflo(q.w), wcol[8 * t + 6], acc);
                    acc = fmaf(bfhi(q.w), wcol[8 * t + 7], acc);
                }
            } else {
                acc = fmaf(xs1[j], wcol[0], acc);
            }
            hrs[il * HIDD + h] = acc;
        }
    }
    __syncthreads();

    // ---- hoist this lane's two hl rows into registers (Phase A operands) ----
    float h0[HIDD], h1[HIDD];
    #pragma unroll
    for (int h = 0; h < HIDD; ++h) {
        h0[h] = hls[lane * 65 + h];
        h1[h] = hls[(lane + 64) * 65 + h];
    }

    // ---- 8 rows per wave; no barriers (as_ is wave-private) ----
    for (int r = 0; r < 8; ++r) {
        const int il = w * 8 + r, i = i0 + il;
        // Phase A: scores, lane = j (two halves)
        float acc0 = 0.f, acc1 = 0.f;
        #pragma unroll
        for (int h = 0; h < HIDD; ++h) {
            float rv = hrs[il * HIDD + h];
            float av = atts[h];
            float e0 = rv + h0[h]; e0 = (e0 > 0.f) ? e0 : 0.2f * e0;
            float e1 = rv + h1[h]; e1 = (e1 > 0.f) ? e1 : 0.2f * e1;
            acc0 = fmaf(av, e0, acc0);
            acc1 = fmaf(av, e1, acc1);
        }
        const float* arow = adjf + ((size_t)b * NN + i) * NN;
        bool a0 = (arow[lane] != 0.f)      || (lane == i);
        bool a1 = (arow[lane + 64] != 0.f) || (lane + 64 == i);
        float s0 = a0 ? acc0 : -1e30f;
        float s1 = a1 ? acc1 : -1e30f;
        // softmax over 128 j
        float mxv = fmaxf(s0, s1);
        for (int o = 32; o >= 1; o >>= 1) mxv = fmaxf(mxv, __shfl_xor(mxv, o, 64));
        float e0 = __expf(s0 - mxv), e1 = __expf(s1 - mxv);
        float sm = e0 + e1;
        for (int o = 32; o >= 1; o >>= 1) sm += __shfl_xor(sm, o, 64);
        float inv = 1.f / sm;
        as_[w][lane]      = e0 * inv;
        as_[w][lane + 64] = e1 * inv;
        // Phase B: aggregation, lane = h
        float acc = 0.f;
        const float* aw = as_[w];
        for (int j = 0; j < NN; ++j) acc = fmaf(aw[j], hls[j * 65 + lane], acc);
        float out = acc + bsv[lane];
        if (skw != nullptr) {
            const float* lr = latr + il * LATD;
            float sk = sbs[lane];
            sk = fmaf(lr[0], sws[0 * HIDD + lane], sk);
            sk = fmaf(lr[1], sws[1 * HIDD + lane], sk);
            sk = fmaf(lr[2], sws[2 * HIDD + lane], sk);
            out += 0.1f * sk;
        }
        out = fmaxf(out, 0.f);
        if constexpr (C == 0) {
            xout[((size_t)b * NN + i) * HIDD + lane] = out;
        } else {
            float hv[C > 0 ? C : 1];
            #pragma unroll
            for (int c = 0; c < C; ++c) {
                float v = out * hws[lane * C + c];
                for (int o = 32; o >= 1; o >>= 1) v += __shfl_xor(v, o, 64);
                hv[c] = v + hbs[c];
            }
            if (lane == 0)
                for (int c = 0; c < C; ++c)
                    head_out[((size_t)b * NN + i) * C + c] = hv[c];
        }
    }
}

// ---------------------------------------------------------------------------
extern "C" void kernel_launch(void* const* d_in, const int* in_sizes, int n_in,
                              void* d_out, int out_size, void* d_ws, size_t ws_size,
                              hipStream_t stream)
{
    const float* batch  = (const float*)d_in[0];
    const float* enc_w1 = (const float*)d_in[1];
    const float* enc_b1 = (const float*)d_in[2];
    const float* enc_w2 = (const float*)d_in[3];
    const float* enc_b2 = (const float*)d_in[4];
    const float* enc_w3 = (const float*)d_in[5];
    const float* enc_b3 = (const float*)d_in[6];
    const float* g_wl[4]  = {(const float*)d_in[7],  (const float*)d_in[13], (const float*)d_in[19], (const float*)d_in[25]};
    const float* g_bl[4]  = {(const float*)d_in[8],  (const float*)d_in[14], (const float*)d_in[20], (const float*)d_in[26]};
    const float* g_wr[4]  = {(const float*)d_in[9],  (const float*)d_in[15], (const float*)d_in[21], (const float*)d_in[27]};
    const float* g_br[4]  = {(const float*)d_in[10], (const float*)d_in[16], (const float*)d_in[22], (const float*)d_in[28]};
    const float* g_att[4] = {(const float*)d_in[11], (const float*)d_in[17], (const float*)d_in[23], (const float*)d_in[29]};
    const float* g_b[4]   = {(const float*)d_in[12], (const float*)d_in[18], (const float*)d_in[24], (const float*)d_in[30]};
    const float* lab_w = (const float*)d_in[31];
    const float* lab_b = (const float*)d_in[32];
    const float* val_w = (const float*)d_in[33];
    const float* val_b = (const float*)d_in[34];
    const float* skw   = (const float*)d_in[35];
    const float* skb   = (const float*)d_in[36];

    float* out = (float*)d_out;
    float* o0 = out;            // batch[:,:,:4]   32768
    float* o1 = out + 32768;    // batch[:,:,4:5]   8192
    float* o2 = out + 40960;    // logits          32768
    float* o3 = out + 73728;    // values           8192
    float* o4 = out + 81920;    // latent          24576  (doubles as latf)
    float* o5 = out + 106496;   // adj           1048576
    float* o6 = out + 1155072;  // edge_dist     1048576

    // Scratch: 4.3 MB in d_ws (round-5 used 4.2 MB successfully).
    char* p = (char*)d_ws;
    auto carve = [&](size_t bytes) { void* r = (void*)p; p += (bytes + 255) & ~(size_t)255; return r; };
    double* aos = (double*)carve((size_t)BB * NN * 4 * 8);       // 256 KB
    float*  xA  = (float*) carve((size_t)BB * NN * HIDD * 4);    // 2 MB
    float*  xB  = (float*) carve((size_t)BB * NN * HIDD * 4);    // 2 MB

    enc_kernel<<<dim3(BB, 4), 256, 0, stream>>>(batch, enc_w1, enc_b1, enc_w2, enc_b2,
                                                enc_w3, enc_b3, aos, o0, o1, o4);
    gabriel_kernel<<<dim3(NN, BB), 128, 0, stream>>>((const P4d*)aos, o5, o6);

    // layer 1 (Cin=1, x0 from o4/latf) -> xA
    gat_kernel<1, 0><<<BB * 4, 256, 0, stream>>>(nullptr, o4,
        g_wl[0], g_bl[0], g_wr[0], g_br[0], g_att[0], g_b[0], o5,
        nullptr, nullptr, xA, nullptr, nullptr, nullptr);
    // layer 2 -> xB (= x2, feeds layers 3 and 4)
    gat_kernel<64, 0><<<BB * 4, 256, 0, stream>>>(xA, o4,
        g_wl[1], g_bl[1], g_wr[1], g_br[1], g_att[1], g_b[1], o5,
        nullptr, nullptr, xB, nullptr, nullptr, nullptr);
    // layer 3 + skip + label head -> o2
    gat_kernel<64, 4><<<BB * 4, 256, 0, stream>>>(xB, o4,
        g_wl[2], g_bl[2], g_wr[2], g_br[2], g_att[2], g_b[2], o5,
        skw, skb, nullptr, lab_w, lab_b, o2);
    // layer 4 + skip + value head -> o3
    gat_kernel<64, 1><<<BB * 4, 256, 0, stream>>>(xB, o4,
        g_wl[3], g_bl[3], g_wr[3], g_br[3], g_att[3], g_b[3], o5,
        skw, skb, nullptr, val_w, val_b, o3);
}

// Round 7
// 393.470 us; speedup vs baseline: 1.2347x; 1.0459x over previous
//
#include <hip/hip_runtime.h>

#define BB 64
#define NN 128
#define INF_ 5
#define LATD 3
#define HIDD 64

// ---------------------------------------------------------------------------
// Encoder (f64, expressions unchanged across rounds -> adjacency bits stable).
// Emits AoS {x,y,z,pk2} f64 for gabriel, o0/o1/o4 (f32). Grid (B,4).
// ---------------------------------------------------------------------------
__global__ __launch_bounds__(256) void enc_kernel(
    const float* __restrict__ batch,
    const float* __restrict__ w1, const float* __restrict__ b1,
    const float* __restrict__ w2, const float* __restrict__ b2,
    const float* __restrict__ w3, const float* __restrict__ b3,
    double* __restrict__ aos,
    float* __restrict__ o0, float* __restrict__ o1, float* __restrict__ o4)
{
    const int b = blockIdx.x;
    const int n0 = blockIdx.y * 32;
    const int tid = threadIdx.x;
    const int w = tid >> 6, lane = tid & 63;

    __shared__ double xs[32][6];
    __shared__ double w1s[INF_][HIDD];
    __shared__ float  w2s[HIDD * HIDD];
    __shared__ double w3s[HIDD][LATD];
    __shared__ double b1s[HIDD], b2s[HIDD], b3s[LATD];

    for (int idx = tid; idx < 32 * INF_; idx += 256) {
        int n = idx / INF_, c = idx % INF_;
        float v = batch[((size_t)b * NN + n0 + n) * INF_ + c];
        xs[n][c] = (double)v;
        if (c < 4) o0[((size_t)b * NN + n0 + n) * 4 + c] = v;
        else       o1[(size_t)b * NN + n0 + n] = v;
    }
    for (int idx = tid; idx < INF_ * HIDD; idx += 256)
        w1s[idx / HIDD][idx % HIDD] = (double)w1[idx];
    for (int idx = tid; idx < HIDD * HIDD; idx += 256)
        w2s[idx] = w2[idx];
    for (int idx = tid; idx < HIDD * LATD; idx += 256)
        w3s[idx / LATD][idx % LATD] = (double)w3[idx];
    if (tid < HIDD) {
        b1s[tid] = (double)b1[tid];
        b2s[tid] = (double)b2[tid];
    }
    if (tid < LATD) b3s[tid] = (double)b3[tid];
    __syncthreads();

    for (int r = 0; r < 8; ++r) {
        const int nl = w * 8 + r;
        const int n = n0 + nl;
        double h1v = b1s[lane];
        for (int k = 0; k < INF_; ++k) h1v += xs[nl][k] * w1s[k][lane];
        h1v = fmax(h1v, 0.0);
        double h2v = b2s[lane];
        for (int k = 0; k < HIDD; ++k) {
            double h1k = __shfl(h1v, k, 64);
            h2v += h1k * (double)w2s[k * HIDD + lane];
        }
        h2v = fmax(h2v, 0.0);
        double l0 = h2v * w3s[lane][0];
        double l1 = h2v * w3s[lane][1];
        double l2 = h2v * w3s[lane][2];
        for (int o = 32; o >= 1; o >>= 1) {
            l0 += __shfl_xor(l0, o, 64);
            l1 += __shfl_xor(l1, o, 64);
            l2 += __shfl_xor(l2, o, 64);
        }
        l0 += b3s[0]; l1 += b3s[1]; l2 += b3s[2];
        if (lane == 0) {
            double* A = aos + ((size_t)b * NN + n) * 4;
            A[0] = l0; A[1] = l1; A[2] = l2;
            A[3] = l0 * l0 + l1 * l1 + l2 * l2;
        }
        if (lane < LATD) {
            double lv = (lane == 0) ? l0 : ((lane == 1) ? l1 : l2);
            o4[((size_t)b * NN + n) * LATD + lane] = (float)lv;
        }
    }
}

// ---------------------------------------------------------------------------
// Gabriel v3: wave = pair (i,j) i<j; LANE = witness k (k and k+64, held in
// registers -> zero memory in the witness test). Pair params from 4 KB LDS
// point table (4 broadcast b128 per pair). Symmetry of the reference's f64
// expressions (fp-commutative in i<->j) lets us compute i<j only and write
// both orders. o5/o6 pre-zeroed by hipMemsetAsync; only edges are stored.
// Row balance: wave v handles rows v (j>v) and 126-v (j>126-v) = 128 pairs.
// Round-6 lesson: do NOT rely on uniform global loads scalarizing.
// ---------------------------------------------------------------------------
__global__ __launch_bounds__(256) void gabriel_kernel(
    const double* __restrict__ aos,
    float* __restrict__ o5, float* __restrict__ o6)
{
    const int b = blockIdx.y;
    const int w = threadIdx.x >> 6, lane = threadIdx.x & 63;
    const int v = blockIdx.x * 4 + w;          // virtual row 0..63

    __shared__ double4 Ps[NN];                 // {x,y,z,pk2}, 4 KB
    const double2* src = (const double2*)(aos + (size_t)b * NN * 4);
    double2* dst = (double2*)Ps;
    for (int idx = threadIdx.x; idx < NN * 2; idx += 256) dst[idx] = src[idx];
    __syncthreads();

    const double4 A  = Ps[lane];               // witness k = lane
    const double4 Bp = Ps[lane + 64];          // witness k = lane+64

    for (int half = 0; half < 2; ++half) {
        const int i = (half == 0) ? v : 126 - v;
        if (half == 1 && i == v) break;        // v==63: single row
        const int jstart = (half == 0) ? (v + 1) : (127 - v);
        const double4 pi = Ps[i];
        const bool miA = (lane != i), miB = (lane + 64 != i);
        for (int j = jstart; j < NN; ++j) {
            double4 pj = Ps[j];
            double dx = pi.x - pj.x, dy = pi.y - pj.y, dz = pi.z - pj.z;
            double s2 = dx * dx + dy * dy + dz * dz;
            double r2 = 0.25 * s2;
            double mx = 0.5 * (pi.x + pj.x), my = 0.5 * (pi.y + pj.y), mz = 0.5 * (pi.z + pj.z);
            double m2 = mx * mx + my * my + mz * mz;
            double dotA = A.x * mx + A.y * my + A.z * mz;
            double dotB = Bp.x * mx + Bp.y * my + Bp.z * mz;
            double dA = A.w - 2.0 * dotA + m2;
            double dB = Bp.w - 2.0 * dotB + m2;
            bool tA = (dA < r2) && miA && (lane != j);
            bool tB = (dB < r2) && miB && (lane + 64 != j);
            if (!__any(tA || tB)) {
                if (lane == 0) {
                    size_t ij = ((size_t)b * NN + i) * NN + j;
                    size_t ji = ((size_t)b * NN + j) * NN + i;
                    float d = (float)sqrt(s2);
                    o5[ij] = 1.0f; o5[ji] = 1.0f;
                    o6[ij] = d;    o6[ji] = d;
                }
            }
        }
    }
}

// ---------------------------------------------------------------------------
// Linear stage: hl = x@wl+bl, hr = x@wr+br for one layer -> global scratch.
// Grid BB*4, 32 nodes/block; lane = h; weights in per-lane registers.
// ---------------------------------------------------------------------------
template <int CIN>
__global__ __launch_bounds__(256) void lin_kernel(
    const float* __restrict__ xin,     // [B,N,64] (CIN==64) else unused
    const float* __restrict__ latf,    // o4 region (CIN==1: x0 = latent[...,2])
    const float* __restrict__ wl, const float* __restrict__ bl,
    const float* __restrict__ wr, const float* __restrict__ br,
    float* __restrict__ hl, float* __restrict__ hr)
{
    const int bx = blockIdx.x;
    const int b = bx >> 2, n0 = (bx & 3) << 5;     // 32 nodes
    const int tid = threadIdx.x, w = tid >> 6, lane = tid & 63;
    __shared__ float xsh[(CIN == 64) ? 32 * 64 : 32];

    if constexpr (CIN == 64) {
        const float4* src = (const float4*)(xin + ((size_t)b * NN + n0) * HIDD);
        float4* dst = (float4*)xsh;
        for (int idx = tid; idx < 32 * 16; idx += 256) dst[idx] = src[idx];
    } else {
        if (tid < 32) xsh[tid] = latf[((size_t)b * NN + n0 + tid) * LATD + 2];
    }
    __syncthreads();

    float wc[CIN];
    #pragma unroll
    for (int k = 0; k < CIN; ++k) wc[k] = wl[k * HIDD + lane];
    float bv = bl[lane];
    for (int m = 0; m < 8; ++m) {
        int nl = w * 8 + m;
        float acc = bv;
        if constexpr (CIN == 64) {
            #pragma unroll
            for (int k = 0; k < CIN; ++k) acc = fmaf(xsh[nl * 64 + k], wc[k], acc);
        } else acc = fmaf(xsh[nl], wc[0], acc);
        hl[((size_t)b * NN + n0 + nl) * HIDD + lane] = acc;
    }
    #pragma unroll
    for (int k = 0; k < CIN; ++k) wc[k] = wr[k * HIDD + lane];
    bv = br[lane];
    for (int m = 0; m < 8; ++m) {
        int nl = w * 8 + m;
        float acc = bv;
        if constexpr (CIN == 64) {
            #pragma unroll
            for (int k = 0; k < CIN; ++k) acc = fmaf(xsh[nl * 64 + k], wc[k], acc);
        } else acc = fmaf(xsh[nl], wc[0], acc);
        hr[((size_t)b * NN + n0 + nl) * HIDD + lane] = acc;
    }
}

// ---------------------------------------------------------------------------
// Attention stage. Grid BB*8 (16 rows/block), ~44 KB LDS -> 2 blocks/CU,
// __launch_bounds__(256,2) -> 2 waves/SIMD for latency hiding. hl staged
// once per block from global (no recompute); stride 68 (b128-aligned).
// Lane hoists its 2 hl rows into registers for Phase A. No row barriers
// (as_ is wave-private). C>0 fuses the output head + ALPHA*skip.
// ---------------------------------------------------------------------------
template <int C>
__global__ __launch_bounds__(256, 2) void attn_kernel(
    const float* __restrict__ hl, const float* __restrict__ hr,
    const float* __restrict__ att, const float* __restrict__ bias,
    const float* __restrict__ adjf,    // o5: f32 0/1, no self loops
    const float* __restrict__ latf,    // o4 region (skip source)
    const float* __restrict__ skw, const float* __restrict__ skb,
    float* __restrict__ xout,          // C==0
    const float* __restrict__ head_w, const float* __restrict__ head_b,
    float* __restrict__ head_out)      // C>0
{
    const int bx = blockIdx.x;
    const int b = bx >> 3, i0 = (bx & 7) << 4;     // 16 rows
    const int tid = threadIdx.x, w = tid >> 6, lane = tid & 63;

    __shared__ float hls[NN * 68];                 // 34.8 KB
    __shared__ float hrs[16 * HIDD];               // 4 KB
    __shared__ float as_[4][NN];                   // 2 KB
    __shared__ float atts[HIDD], bsv[HIDD];
    __shared__ float hws[(C > 0) ? HIDD * C : 1], hbs[(C > 0) ? C : 1];
    __shared__ float sws[LATD * HIDD], sbs[HIDD];
    __shared__ float latr[16 * LATD];

    {
        const float4* src = (const float4*)(hl + (size_t)b * NN * HIDD);
        for (int idx = tid; idx < NN * 16; idx += 256) {
            int j = idx >> 4, c = idx & 15;
            *(float4*)&hls[j * 68 + 4 * c] = src[idx];
        }
        const float4* srcr = (const float4*)(hr + ((size_t)b * NN + i0) * HIDD);
        for (int idx = tid; idx < 16 * 16; idx += 256)
            ((float4*)hrs)[idx] = srcr[idx];
    }
    if (tid < HIDD) { atts[tid] = att[tid]; bsv[tid] = bias[tid]; }
    if constexpr (C > 0) {
        for (int idx = tid; idx < HIDD * C; idx += 256) hws[idx] = head_w[idx];
        if (tid < C) hbs[tid] = head_b[tid];
    }
    if (skw != nullptr) {
        for (int idx = tid; idx < LATD * HIDD; idx += 256) sws[idx] = skw[idx];
        if (tid < HIDD) sbs[tid] = skb[tid];
        if (tid < 16 * LATD) latr[tid] = latf[((size_t)b * NN + i0) * LATD + tid];
    }
    __syncthreads();

    float h0[HIDD], h1[HIDD];
    #pragma unroll
    for (int h = 0; h < HIDD; ++h) {
        h0[h] = hls[lane * 68 + h];
        h1[h] = hls[(lane + 64) * 68 + h];
    }

    for (int r = 0; r < 4; ++r) {
        const int il = w * 4 + r, i = i0 + il;
        float acc0 = 0.f, acc1 = 0.f;
        #pragma unroll
        for (int h = 0; h < HIDD; ++h) {
            float rv = hrs[il * HIDD + h], av = atts[h];
            float e0 = rv + h0[h]; e0 = (e0 > 0.f) ? e0 : 0.2f * e0;
            float e1 = rv + h1[h]; e1 = (e1 > 0.f) ? e1 : 0.2f * e1;
            acc0 = fmaf(av, e0, acc0);
            acc1 = fmaf(av, e1, acc1);
        }
        const float* arow = adjf + ((size_t)b * NN + i) * NN;
        bool a0 = (arow[lane] != 0.f)      || (lane == i);
        bool a1 = (arow[lane + 64] != 0.f) || (lane + 64 == i);
        float s0 = a0 ? acc0 : -1e30f;
        float s1 = a1 ? acc1 : -1e30f;
        float mxv = fmaxf(s0, s1);
        for (int o = 32; o >= 1; o >>= 1) mxv = fmaxf(mxv, __shfl_xor(mxv, o, 64));
        float e0 = __expf(s0 - mxv), e1 = __expf(s1 - mxv);
        float sm = e0 + e1;
        for (int o = 32; o >= 1; o >>= 1) sm += __shfl_xor(sm, o, 64);
        float inv = 1.f / sm;
        as_[w][lane]      = e0 * inv;
        as_[w][lane + 64] = e1 * inv;
        float acc = 0.f;
        for (int j = 0; j < NN; ++j) acc = fmaf(as_[w][j], hls[j * 68 + lane], acc);
        float out = acc + bsv[lane];
        if (skw != nullptr) {
            const float* lr = latr + il * LATD;
            float sk = sbs[lane];
            sk = fmaf(lr[0], sws[lane], sk);
            sk = fmaf(lr[1], sws[64 + lane], sk);
            sk = fmaf(lr[2], sws[128 + lane], sk);
            out += 0.1f * sk;
        }
        out = fmaxf(out, 0.f);
        if constexpr (C == 0) {
            xout[((size_t)b * NN + i) * HIDD + lane] = out;
        } else {
            float hv[C > 0 ? C : 1];
            #pragma unroll
            for (int c = 0; c < C; ++c) {
                float v = out * hws[lane * C + c];
                for (int o = 32; o >= 1; o >>= 1) v += __shfl_xor(v, o, 64);
                hv[c] = v + hbs[c];
            }
            if (lane == 0)
                for (int c = 0; c < C; ++c)
                    head_out[((size_t)b * NN + i) * C + c] = hv[c];
        }
    }
}

// ---------------------------------------------------------------------------
extern "C" void kernel_launch(void* const* d_in, const int* in_sizes, int n_in,
                              void* d_out, int out_size, void* d_ws, size_t ws_size,
                              hipStream_t stream)
{
    const float* batch  = (const float*)d_in[0];
    const float* enc_w1 = (const float*)d_in[1];
    const float* enc_b1 = (const float*)d_in[2];
    const float* enc_w2 = (const float*)d_in[3];
    const float* enc_b2 = (const float*)d_in[4];
    const float* enc_w3 = (const float*)d_in[5];
    const float* enc_b3 = (const float*)d_in[6];
    const float* g_wl[4]  = {(const float*)d_in[7],  (const float*)d_in[13], (const float*)d_in[19], (const float*)d_in[25]};
    const float* g_bl[4]  = {(const float*)d_in[8],  (const float*)d_in[14], (const float*)d_in[20], (const float*)d_in[26]};
    const float* g_wr[4]  = {(const float*)d_in[9],  (const float*)d_in[15], (const float*)d_in[21], (const float*)d_in[27]};
    const float* g_br[4]  = {(const float*)d_in[10], (const float*)d_in[16], (const float*)d_in[22], (const float*)d_in[28]};
    const float* g_att[4] = {(const float*)d_in[11], (const float*)d_in[17], (const float*)d_in[23], (const float*)d_in[29]};
    const float* g_b[4]   = {(const float*)d_in[12], (const float*)d_in[18], (const float*)d_in[24], (const float*)d_in[30]};
    const float* lab_w = (const float*)d_in[31];
    const float* lab_b = (const float*)d_in[32];
    const float* val_w = (const float*)d_in[33];
    const float* val_b = (const float*)d_in[34];
    const float* skw   = (const float*)d_in[35];
    const float* skb   = (const float*)d_in[36];

    float* out = (float*)d_out;
    float* o0 = out;            // batch[:,:,:4]   32768
    float* o1 = out + 32768;    // batch[:,:,4:5]   8192
    float* o2 = out + 40960;    // logits          32768
    float* o3 = out + 73728;    // values           8192
    float* o4 = out + 81920;    // latent          24576  (doubles as latf)
    float* o5 = out + 106496;   // adj           1048576
    float* o6 = out + 1155072;  // edge_dist     1048576

    // Scratch: 8.3 MB (rounds 1-2 carved 11.8 MB successfully).
    char* p = (char*)d_ws;
    auto carve = [&](size_t bytes) { void* r = (void*)p; p += (bytes + 255) & ~(size_t)255; return r; };
    double* aos = (double*)carve((size_t)BB * NN * 4 * 8);       // 256 KB
    float*  xA  = (float*) carve((size_t)BB * NN * HIDD * 4);    // 2 MB
    float*  xB  = (float*) carve((size_t)BB * NN * HIDD * 4);    // 2 MB
    float*  hlw = (float*) carve((size_t)BB * NN * HIDD * 4);    // 2 MB
    float*  hrw = (float*) carve((size_t)BB * NN * HIDD * 4);    // 2 MB

    enc_kernel<<<dim3(BB, 4), 256, 0, stream>>>(batch, enc_w1, enc_b1, enc_w2, enc_b2,
                                                enc_w3, enc_b3, aos, o0, o1, o4);
    // zero adj/edge_dist (contiguous 8 MB); gabriel writes edges only
    hipMemsetAsync(o5, 0, (size_t)2 * 1048576 * 4, stream);
    gabriel_kernel<<<dim3(16, BB), 256, 0, stream>>>(aos, o5, o6);

    // layer 1 (Cin=1, x0 = latent[...,2]) -> xA
    lin_kernel<1><<<BB * 4, 256, 0, stream>>>(nullptr, o4, g_wl[0], g_bl[0], g_wr[0], g_br[0], hlw, hrw);
    attn_kernel<0><<<BB * 8, 256, 0, stream>>>(hlw, hrw, g_att[0], g_b[0], o5, o4,
                                               nullptr, nullptr, xA, nullptr, nullptr, nullptr);
    // layer 2 -> xB
    lin_kernel<64><<<BB * 4, 256, 0, stream>>>(xA, o4, g_wl[1], g_bl[1], g_wr[1], g_br[1], hlw, hrw);
    attn_kernel<0><<<BB * 8, 256, 0, stream>>>(hlw, hrw, g_att[1], g_b[1], o5, o4,
                                               nullptr, nullptr, xB, nullptr, nullptr, nullptr);
    // layer 3 + skip + label head -> o2
    lin_kernel<64><<<BB * 4, 256, 0, stream>>>(xB, o4, g_wl[2], g_bl[2], g_wr[2], g_br[2], hlw, hrw);
    attn_kernel<4><<<BB * 8, 256, 0, stream>>>(hlw, hrw, g_att[2], g_b[2], o5, o4,
                                               skw, skb, nullptr, lab_w, lab_b, o2);
    // layer 4 + skip + value head -> o3
    lin_kernel<64><<<BB * 4, 256, 0, stream>>>(xB, o4, g_wl[3], g_bl[3], g_wr[3], g_br[3], hlw, hrw);
    attn_kernel<1><<<BB * 8, 256, 0, stream>>>(hlw, hrw, g_att[3], g_b[3], o5, o4,
                                               skw, skb, nullptr, val_w, val_b, o3);
}

// Round 8
// 311.511 us; speedup vs baseline: 1.5595x; 1.2631x over previous
//
#include <hip/hip_runtime.h>

#define BB 64
#define NN 128
#define INF_ 5
#define LATD 3
#define HIDD 64

// ---------------------------------------------------------------------------
// Encoder (f64, expressions unchanged across rounds -> adjacency bits stable).
// Emits AoS {x,y,z,pk2} f64 for gabriel, o0/o1/o4 (f32). Grid (B,4).
// ---------------------------------------------------------------------------
__global__ __launch_bounds__(256) void enc_kernel(
    const float* __restrict__ batch,
    const float* __restrict__ w1, const float* __restrict__ b1,
    const float* __restrict__ w2, const float* __restrict__ b2,
    const float* __restrict__ w3, const float* __restrict__ b3,
    double* __restrict__ aos,
    float* __restrict__ o0, float* __restrict__ o1, float* __restrict__ o4)
{
    const int b = blockIdx.x;
    const int n0 = blockIdx.y * 32;
    const int tid = threadIdx.x;
    const int w = tid >> 6, lane = tid & 63;

    __shared__ double xs[32][6];
    __shared__ double w1s[INF_][HIDD];
    __shared__ float  w2s[HIDD * HIDD];
    __shared__ double w3s[HIDD][LATD];
    __shared__ double b1s[HIDD], b2s[HIDD], b3s[LATD];

    for (int idx = tid; idx < 32 * INF_; idx += 256) {
        int n = idx / INF_, c = idx % INF_;
        float v = batch[((size_t)b * NN + n0 + n) * INF_ + c];
        xs[n][c] = (double)v;
        if (c < 4) o0[((size_t)b * NN + n0 + n) * 4 + c] = v;
        else       o1[(size_t)b * NN + n0 + n] = v;
    }
    for (int idx = tid; idx < INF_ * HIDD; idx += 256)
        w1s[idx / HIDD][idx % HIDD] = (double)w1[idx];
    for (int idx = tid; idx < HIDD * HIDD; idx += 256)
        w2s[idx] = w2[idx];
    for (int idx = tid; idx < HIDD * LATD; idx += 256)
        w3s[idx / LATD][idx % LATD] = (double)w3[idx];
    if (tid < HIDD) {
        b1s[tid] = (double)b1[tid];
        b2s[tid] = (double)b2[tid];
    }
    if (tid < LATD) b3s[tid] = (double)b3[tid];
    __syncthreads();

    for (int r = 0; r < 8; ++r) {
        const int nl = w * 8 + r;
        const int n = n0 + nl;
        double h1v = b1s[lane];
        for (int k = 0; k < INF_; ++k) h1v += xs[nl][k] * w1s[k][lane];
        h1v = fmax(h1v, 0.0);
        double h2v = b2s[lane];
        for (int k = 0; k < HIDD; ++k) {
            double h1k = __shfl(h1v, k, 64);
            h2v += h1k * (double)w2s[k * HIDD + lane];
        }
        h2v = fmax(h2v, 0.0);
        double l0 = h2v * w3s[lane][0];
        double l1 = h2v * w3s[lane][1];
        double l2 = h2v * w3s[lane][2];
        for (int o = 32; o >= 1; o >>= 1) {
            l0 += __shfl_xor(l0, o, 64);
            l1 += __shfl_xor(l1, o, 64);
            l2 += __shfl_xor(l2, o, 64);
        }
        l0 += b3s[0]; l1 += b3s[1]; l2 += b3s[2];
        if (lane == 0) {
            double* A = aos + ((size_t)b * NN + n) * 4;
            A[0] = l0; A[1] = l1; A[2] = l2;
            A[3] = l0 * l0 + l1 * l1 + l2 * l2;
        }
        if (lane < LATD) {
            double lv = (lane == 0) ? l0 : ((lane == 1) ? l1 : l2);
            o4[((size_t)b * NN + n) * LATD + lane] = (float)lv;
        }
    }
}

// ---------------------------------------------------------------------------
// Gabriel v4: wave = pair stream, lane = witness k (registers). Blocking test
// uses the exact algebraic identity d2 - r2 == (pk-pi).(pk-pj): blocked iff
// that dot < 0. f64; (pk-pi) hoisted per row -> ~14 f64 ops per pair (was
// ~28). s2/sqrt only computed when an edge is found (Gabriel graphs are
// sparse). Symmetric: compute i<j, write both orders into memset-zeroed o5/o6.
// ---------------------------------------------------------------------------
__global__ __launch_bounds__(256) void gabriel_kernel(
    const double* __restrict__ aos,
    float* __restrict__ o5, float* __restrict__ o6)
{
    const int b = blockIdx.y;
    const int w = threadIdx.x >> 6, lane = threadIdx.x & 63;
    const int v = blockIdx.x * 4 + w;          // virtual row 0..63

    __shared__ double4 Ps[NN];                 // {x,y,z,pk2}, 4 KB
    const double2* src = (const double2*)(aos + (size_t)b * NN * 4);
    double2* dst = (double2*)Ps;
    for (int idx = threadIdx.x; idx < NN * 2; idx += 256) dst[idx] = src[idx];
    __syncthreads();

    const double4 A  = Ps[lane];               // witness k = lane
    const double4 Bq = Ps[lane + 64];          // witness k = lane+64

    for (int half = 0; half < 2; ++half) {
        const int i = (half == 0) ? v : 126 - v;
        if (half == 1 && i == v) break;        // v==63: single row
        const int jstart = (half == 0) ? (v + 1) : (127 - v);
        const double4 pi = Ps[i];
        // hoisted: (pk - pi) for this row's fixed i
        const double aix = A.x - pi.x,  aiy = A.y - pi.y,  aiz = A.z - pi.z;
        const double bix = Bq.x - pi.x, biy = Bq.y - pi.y, biz = Bq.z - pi.z;
        const bool mA = (lane != i), mB = (lane + 64 != i);
        for (int j = jstart; j < NN; ++j) {
            double4 pj = Ps[j];
            double ajx = A.x - pj.x,  ajy = A.y - pj.y,  ajz = A.z - pj.z;
            double bjx = Bq.x - pj.x, bjy = Bq.y - pj.y, bjz = Bq.z - pj.z;
            double dA = aix * ajx + aiy * ajy + aiz * ajz;   // = d2 - r2 (exact algebra)
            double dB = bix * bjx + biy * bjy + biz * bjz;
            bool tA = (dA < 0.0) && mA && (lane != j);
            bool tB = (dB < 0.0) && mB && (lane + 64 != j);
            if (!__any(tA || tB)) {
                if (lane == 0) {
                    double dx = pi.x - pj.x, dy = pi.y - pj.y, dz = pi.z - pj.z;
                    float d = (float)sqrt(dx * dx + dy * dy + dz * dz);
                    size_t ij = ((size_t)b * NN + i) * NN + j;
                    size_t ji = ((size_t)b * NN + j) * NN + i;
                    o5[ij] = 1.0f; o5[ji] = 1.0f;
                    o6[ij] = d;    o6[ji] = d;
                }
            }
        }
    }
}

// ---------------------------------------------------------------------------
// Linear stage: hl = x@wl+bl, hr = x@wr+br -> global scratch. Grid BB*4,
// 32 nodes/block; lane = h; weights in per-lane registers (coalesced global);
// x broadcasts vectorized to b128 (4x fewer LDS issues than round 7).
// ---------------------------------------------------------------------------
template <int CIN>
__global__ __launch_bounds__(256) void lin_kernel(
    const float* __restrict__ xin,     // [B,N,64] (CIN==64) else unused
    const float* __restrict__ latf,    // o4 region (CIN==1: x0 = latent[...,2])
    const float* __restrict__ wl, const float* __restrict__ bl,
    const float* __restrict__ wr, const float* __restrict__ br,
    float* __restrict__ hl, float* __restrict__ hr)
{
    const int bx = blockIdx.x;
    const int b = bx >> 2, n0 = (bx & 3) << 5;     // 32 nodes
    const int tid = threadIdx.x, w = tid >> 6, lane = tid & 63;
    __shared__ float4 xs4[(CIN == 64) ? 32 * 16 : 8];
    float* xsh = (float*)xs4;

    if constexpr (CIN == 64) {
        const float4* src = (const float4*)(xin + ((size_t)b * NN + n0) * HIDD);
        for (int idx = tid; idx < 32 * 16; idx += 256) xs4[idx] = src[idx];
    } else {
        if (tid < 32) xsh[tid] = latf[((size_t)b * NN + n0 + tid) * LATD + 2];
    }
    __syncthreads();

    float wc[CIN];
    #pragma unroll
    for (int k = 0; k < CIN; ++k) wc[k] = wl[k * HIDD + lane];
    float bv = bl[lane];
    for (int m = 0; m < 8; ++m) {
        int nl = w * 8 + m;
        float acc = bv;
        if constexpr (CIN == 64) {
            #pragma unroll
            for (int t = 0; t < 16; ++t) {
                float4 q = xs4[nl * 16 + t];
                acc = fmaf(q.x, wc[4 * t + 0], acc);
                acc = fmaf(q.y, wc[4 * t + 1], acc);
                acc = fmaf(q.z, wc[4 * t + 2], acc);
                acc = fmaf(q.w, wc[4 * t + 3], acc);
            }
        } else acc = fmaf(xsh[nl], wc[0], acc);
        hl[((size_t)b * NN + n0 + nl) * HIDD + lane] = acc;
    }
    #pragma unroll
    for (int k = 0; k < CIN; ++k) wc[k] = wr[k * HIDD + lane];
    bv = br[lane];
    for (int m = 0; m < 8; ++m) {
        int nl = w * 8 + m;
        float acc = bv;
        if constexpr (CIN == 64) {
            #pragma unroll
            for (int t = 0; t < 16; ++t) {
                float4 q = xs4[nl * 16 + t];
                acc = fmaf(q.x, wc[4 * t + 0], acc);
                acc = fmaf(q.y, wc[4 * t + 1], acc);
                acc = fmaf(q.z, wc[4 * t + 2], acc);
                acc = fmaf(q.w, wc[4 * t + 3], acc);
            }
        } else acc = fmaf(xsh[nl], wc[0], acc);
        hr[((size_t)b * NN + n0 + nl) * HIDD + lane] = acc;
    }
}

// ---------------------------------------------------------------------------
// Attention stage, LDS-issue minimized (round-7 was LDS-port bound):
//  * h0/h1 hoist via b128 ((17*lane+c)%32, 17 odd -> conflict-free), was
//    8-way conflicted b32.
//  * Phase A: hrs/atts read as b128 broadcasts (4x fewer issues).
//  * Phase B: JOINT over the wave's 4 rows — a packed as float4 per j, one
//    hls read + one b128 broadcast feeds 4 accumulators (4x fewer issues).
// Grid BB*8 (16 rows/block), ~50 KB LDS -> 2 blocks/CU.
// ---------------------------------------------------------------------------
template <int C>
__global__ __launch_bounds__(256, 2) void attn_kernel(
    const float* __restrict__ hl, const float* __restrict__ hr,
    const float* __restrict__ att, const float* __restrict__ bias,
    const float* __restrict__ adjf,    // o5: f32 0/1, no self loops
    const float* __restrict__ latf,    // o4 region (skip source)
    const float* __restrict__ skw, const float* __restrict__ skb,
    float* __restrict__ xout,          // C==0
    const float* __restrict__ head_w, const float* __restrict__ head_b,
    float* __restrict__ head_out)      // C>0
{
    const int bx = blockIdx.x;
    const int b = bx >> 3, i0 = (bx & 7) << 4;     // 16 rows
    const int tid = threadIdx.x, w = tid >> 6, lane = tid & 63;

    __shared__ __align__(16) float hls[NN * 68];   // 34.8 KB
    __shared__ __align__(16) float hrs[16 * HIDD]; // 4 KB
    __shared__ float4 as4[4][NN];                  // 8 KB (wave-private rows)
    __shared__ __align__(16) float atts[HIDD];
    __shared__ float bsv[HIDD];
    __shared__ float hws[(C > 0) ? HIDD * C : 1], hbs[(C > 0) ? C : 1];
    __shared__ float sws[LATD * HIDD], sbs[HIDD];
    __shared__ float latr[16 * LATD];

    {
        const float4* src = (const float4*)(hl + (size_t)b * NN * HIDD);
        for (int idx = tid; idx < NN * 16; idx += 256) {
            int j = idx >> 4, c = idx & 15;
            *(float4*)&hls[j * 68 + 4 * c] = src[idx];
        }
        const float4* srcr = (const float4*)(hr + ((size_t)b * NN + i0) * HIDD);
        for (int idx = tid; idx < 16 * 16; idx += 256)
            ((float4*)hrs)[idx] = srcr[idx];
    }
    if (tid < HIDD) { atts[tid] = att[tid]; bsv[tid] = bias[tid]; }
    if constexpr (C > 0) {
        for (int idx = tid; idx < HIDD * C; idx += 256) hws[idx] = head_w[idx];
        if (tid < C) hbs[tid] = head_b[tid];
    }
    if (skw != nullptr) {
        for (int idx = tid; idx < LATD * HIDD; idx += 256) sws[idx] = skw[idx];
        if (tid < HIDD) sbs[tid] = skb[tid];
        if (tid < 16 * LATD) latr[tid] = latf[((size_t)b * NN + i0) * LATD + tid];
    }
    __syncthreads();

    // hoist this lane's two hl rows (b128, conflict-free: stride 17 float4s)
    float h0[HIDD], h1[HIDD];
    #pragma unroll
    for (int t = 0; t < 16; ++t) {
        float4 q0 = *(const float4*)&hls[lane * 68 + 4 * t];
        float4 q1 = *(const float4*)&hls[(lane + 64) * 68 + 4 * t];
        h0[4 * t + 0] = q0.x; h0[4 * t + 1] = q0.y; h0[4 * t + 2] = q0.z; h0[4 * t + 3] = q0.w;
        h1[4 * t + 0] = q1.x; h1[4 * t + 1] = q1.y; h1[4 * t + 2] = q1.z; h1[4 * t + 3] = q1.w;
    }

    // ---- Phase A: 4 softmaxes ----
    float a0[4], a1[4];
    #pragma unroll
    for (int r = 0; r < 4; ++r) {
        const int il = w * 4 + r, i = i0 + il;
        float acc0 = 0.f, acc1 = 0.f;
        #pragma unroll
        for (int t = 0; t < 16; ++t) {
            float4 rv = *(const float4*)&hrs[il * HIDD + 4 * t];  // broadcast
            float4 av = *(const float4*)&atts[4 * t];             // broadcast
            float e;
            e = rv.x + h0[4 * t + 0]; e = (e > 0.f) ? e : 0.2f * e; acc0 = fmaf(av.x, e, acc0);
            e = rv.y + h0[4 * t + 1]; e = (e > 0.f) ? e : 0.2f * e; acc0 = fmaf(av.y, e, acc0);
            e = rv.z + h0[4 * t + 2]; e = (e > 0.f) ? e : 0.2f * e; acc0 = fmaf(av.z, e, acc0);
            e = rv.w + h0[4 * t + 3]; e = (e > 0.f) ? e : 0.2f * e; acc0 = fmaf(av.w, e, acc0);
            e = rv.x + h1[4 * t + 0]; e = (e > 0.f) ? e : 0.2f * e; acc1 = fmaf(av.x, e, acc1);
            e = rv.y + h1[4 * t + 1]; e = (e > 0.f) ? e : 0.2f * e; acc1 = fmaf(av.y, e, acc1);
            e = rv.z + h1[4 * t + 2]; e = (e > 0.f) ? e : 0.2f * e; acc1 = fmaf(av.z, e, acc1);
            e = rv.w + h1[4 * t + 3]; e = (e > 0.f) ? e : 0.2f * e; acc1 = fmaf(av.w, e, acc1);
        }
        const float* arow = adjf + ((size_t)b * NN + i) * NN;
        bool ad0 = (arow[lane] != 0.f)      || (lane == i);
        bool ad1 = (arow[lane + 64] != 0.f) || (lane + 64 == i);
        float s0 = ad0 ? acc0 : -1e30f;
        float s1 = ad1 ? acc1 : -1e30f;
        float mxv = fmaxf(s0, s1);
        for (int o = 32; o >= 1; o >>= 1) mxv = fmaxf(mxv, __shfl_xor(mxv, o, 64));
        float e0 = __expf(s0 - mxv), e1 = __expf(s1 - mxv);
        float sm = e0 + e1;
        for (int o = 32; o >= 1; o >>= 1) sm += __shfl_xor(sm, o, 64);
        float inv = 1.f / sm;
        a0[r] = e0 * inv;
        a1[r] = e1 * inv;
    }
    as4[w][lane]      = make_float4(a0[0], a0[1], a0[2], a0[3]);
    as4[w][lane + 64] = make_float4(a1[0], a1[1], a1[2], a1[3]);
    // wave-private LDS; compiler's lgkmcnt ordering suffices (no barrier)

    // ---- Phase B: joint aggregation for 4 rows ----
    float acc[4] = {0.f, 0.f, 0.f, 0.f};
    for (int j = 0; j < NN; ++j) {
        float4 av = as4[w][j];                 // broadcast
        float hv = hls[j * 68 + lane];         // conflict-free (2-way alias)
        acc[0] = fmaf(av.x, hv, acc[0]);
        acc[1] = fmaf(av.y, hv, acc[1]);
        acc[2] = fmaf(av.z, hv, acc[2]);
        acc[3] = fmaf(av.w, hv, acc[3]);
    }

    // ---- epilogue ----
    #pragma unroll
    for (int r = 0; r < 4; ++r) {
        const int il = w * 4 + r, i = i0 + il;
        float out = acc[r] + bsv[lane];
        if (skw != nullptr) {
            const float* lr = latr + il * LATD;
            float sk = sbs[lane];
            sk = fmaf(lr[0], sws[lane], sk);
            sk = fmaf(lr[1], sws[64 + lane], sk);
            sk = fmaf(lr[2], sws[128 + lane], sk);
            out += 0.1f * sk;
        }
        out = fmaxf(out, 0.f);
        if constexpr (C == 0) {
            xout[((size_t)b * NN + i) * HIDD + lane] = out;
        } else {
            float hv[C > 0 ? C : 1];
            #pragma unroll
            for (int c = 0; c < C; ++c) {
                float vv = out * hws[lane * C + c];
                for (int o = 32; o >= 1; o >>= 1) vv += __shfl_xor(vv, o, 64);
                hv[c] = vv + hbs[c];
            }
            if (lane == 0)
                for (int c = 0; c < C; ++c)
                    head_out[((size_t)b * NN + i) * C + c] = hv[c];
        }
    }
}

// ---------------------------------------------------------------------------
extern "C" void kernel_launch(void* const* d_in, const int* in_sizes, int n_in,
                              void* d_out, int out_size, void* d_ws, size_t ws_size,
                              hipStream_t stream)
{
    const float* batch  = (const float*)d_in[0];
    const float* enc_w1 = (const float*)d_in[1];
    const float* enc_b1 = (const float*)d_in[2];
    const float* enc_w2 = (const float*)d_in[3];
    const float* enc_b2 = (const float*)d_in[4];
    const float* enc_w3 = (const float*)d_in[5];
    const float* enc_b3 = (const float*)d_in[6];
    const float* g_wl[4]  = {(const float*)d_in[7],  (const float*)d_in[13], (const float*)d_in[19], (const float*)d_in[25]};
    const float* g_bl[4]  = {(const float*)d_in[8],  (const float*)d_in[14], (const float*)d_in[20], (const float*)d_in[26]};
    const float* g_wr[4]  = {(const float*)d_in[9],  (const float*)d_in[15], (const float*)d_in[21], (const float*)d_in[27]};
    const float* g_br[4]  = {(const float*)d_in[10], (const float*)d_in[16], (const float*)d_in[22], (const float*)d_in[28]};
    const float* g_att[4] = {(const float*)d_in[11], (const float*)d_in[17], (const float*)d_in[23], (const float*)d_in[29]};
    const float* g_b[4]   = {(const float*)d_in[12], (const float*)d_in[18], (const float*)d_in[24], (const float*)d_in[30]};
    const float* lab_w = (const float*)d_in[31];
    const float* lab_b = (const float*)d_in[32];
    const float* val_w = (const float*)d_in[33];
    const float* val_b = (const float*)d_in[34];
    const float* skw   = (const float*)d_in[35];
    const float* skb   = (const float*)d_in[36];

    float* out = (float*)d_out;
    float* o0 = out;            // batch[:,:,:4]   32768
    float* o1 = out + 32768;    // batch[:,:,4:5]   8192
    float* o2 = out + 40960;    // logits          32768
    float* o3 = out + 73728;    // values           8192
    float* o4 = out + 81920;    // latent          24576  (doubles as latf)
    float* o5 = out + 106496;   // adj           1048576
    float* o6 = out + 1155072;  // edge_dist     1048576

    char* p = (char*)d_ws;
    auto carve = [&](size_t bytes) { void* r = (void*)p; p += (bytes + 255) & ~(size_t)255; return r; };
    double* aos = (double*)carve((size_t)BB * NN * 4 * 8);       // 256 KB
    float*  xA  = (float*) carve((size_t)BB * NN * HIDD * 4);    // 2 MB
    float*  xB  = (float*) carve((size_t)BB * NN * HIDD * 4);    // 2 MB
    float*  hlw = (float*) carve((size_t)BB * NN * HIDD * 4);    // 2 MB
    float*  hrw = (float*) carve((size_t)BB * NN * HIDD * 4);    // 2 MB

    enc_kernel<<<dim3(BB, 4), 256, 0, stream>>>(batch, enc_w1, enc_b1, enc_w2, enc_b2,
                                                enc_w3, enc_b3, aos, o0, o1, o4);
    hipMemsetAsync(o5, 0, (size_t)2 * 1048576 * 4, stream);
    gabriel_kernel<<<dim3(16, BB), 256, 0, stream>>>(aos, o5, o6);

    // layer 1 (Cin=1, x0 = latent[...,2]) -> xA
    lin_kernel<1><<<BB * 4, 256, 0, stream>>>(nullptr, o4, g_wl[0], g_bl[0], g_wr[0], g_br[0], hlw, hrw);
    attn_kernel<0><<<BB * 8, 256, 0, stream>>>(hlw, hrw, g_att[0], g_b[0], o5, o4,
                                               nullptr, nullptr, xA, nullptr, nullptr, nullptr);
    // layer 2 -> xB
    lin_kernel<64><<<BB * 4, 256, 0, stream>>>(xA, o4, g_wl[1], g_bl[1], g_wr[1], g_br[1], hlw, hrw);
    attn_kernel<0><<<BB * 8, 256, 0, stream>>>(hlw, hrw, g_att[1], g_b[1], o5, o4,
                                               nullptr, nullptr, xB, nullptr, nullptr, nullptr);
    // layer 3 + skip + label head -> o2
    lin_kernel<64><<<BB * 4, 256, 0, stream>>>(xB, o4, g_wl[2], g_bl[2], g_wr[2], g_br[2], hlw, hrw);
    attn_kernel<4><<<BB * 8, 256, 0, stream>>>(hlw, hrw, g_att[2], g_b[2], o5, o4,
                                               skw, skb, nullptr, lab_w, lab_b, o2);
    // layer 4 + skip + value head -> o3
    lin_kernel<64><<<BB * 4, 256, 0, stream>>>(xB, o4, g_wl[3], g_bl[3], g_wr[3], g_br[3], hlw, hrw);
    attn_kernel<1><<<BB * 8, 256, 0, stream>>>(hlw, hrw, g_att[3], g_b[3], o5, o4,
                                               skw, skb, nullptr, val_w, val_b, o3);
}